// Round 7
// baseline (775.725 us; speedup 1.0000x reference)
//
#include <hip/hip_runtime.h>
#include <math.h>

#define N_NODES 50000
#define N_EDGES 800000
#define D 128
#define AVG_D_LOG 2.833213344056216f  /* log(17.0) */
#define EPS 1e-5f

typedef __attribute__((ext_vector_type(8))) short bf16x8;
typedef __attribute__((ext_vector_type(4))) float f32x4;

__device__ __forceinline__ unsigned short f2bf(float x) {
    unsigned u = __float_as_uint(x);
    u += 0x7fffu + ((u >> 16) & 1u);
    return (unsigned short)(u >> 16);
}
__device__ __forceinline__ unsigned pk2bf(float a, float b) {
    return (unsigned)f2bf(a) | ((unsigned)f2bf(b) << 16);
}
__device__ __forceinline__ float bf2f(unsigned short u) {
    return __uint_as_float(((unsigned)u) << 16);
}

// ---------------- init: zero accumulators, +inf for min, zero hist ----------------
__global__ void k_init(int* hist, float* s1, float* s2, float* mx, float* mn) {
    size_t stride = (size_t)gridDim.x * blockDim.x;
    size_t i0 = (size_t)blockIdx.x * blockDim.x + threadIdx.x;
    const size_t ND4 = (size_t)N_NODES * D / 4;
    float4 z4 = {0.f, 0.f, 0.f, 0.f};
    int4 inf4 = {0x7f800000, 0x7f800000, 0x7f800000, 0x7f800000};
    for (size_t t = i0; t < ND4; t += stride) {
        ((float4*)s1)[t] = z4; ((float4*)s2)[t] = z4; ((float4*)mx)[t] = z4;
        ((int4*)mn)[t] = inf4;
    }
    for (size_t t = i0; t < N_NODES; t += stride) hist[t] = 0;
}

// ---------------- CSR build ----------------
__global__ void k_hist(const int* __restrict__ dst, int* hist) {
    int e = blockIdx.x * blockDim.x + threadIdx.x;
    if (e < N_EDGES) atomicAdd(&hist[dst[e]], 1);
}

__global__ void k_scan(const int* __restrict__ hist, int* cursor) {
    __shared__ int part[256];
    __shared__ int base_s[256];
    int t = threadIdx.x;
    const int chunk = (N_NODES + 255) / 256;
    int lo = t * chunk;
    int hi = lo + chunk; if (hi > N_NODES) hi = N_NODES;
    int s = 0;
    for (int i = lo; i < hi; ++i) s += hist[i];
    part[t] = s;
    __syncthreads();
    if (t == 0) {
        int run = 0;
        for (int i = 0; i < 256; ++i) { base_s[i] = run; run += part[i]; }
    }
    __syncthreads();
    int run = base_s[t];
    for (int i = lo; i < hi; ++i) { cursor[i] = run; run += hist[i]; }
}

__global__ void k_scatter(const int* __restrict__ dst, int* cursor, int* perm) {
    int e = blockIdx.x * blockDim.x + threadIdx.x;
    if (e < N_EDGES) {
        int pos = atomicAdd(&cursor[dst[e]], 1);
        perm[pos] = e;
    }
}

// ---------------- one-time: W [K][128] fp32 -> WT [128][K] bf16 ----------------
__global__ void k_prepT(const float* __restrict__ w, unsigned short* __restrict__ wT, int K) {
    int idx = blockIdx.x * blockDim.x + threadIdx.x;
    if (idx >= K * D) return;
    int k = idx >> 7, c = idx & 127;
    wT[(size_t)c * K + k] = f2bf(w[idx]);
}

// ---------------- pretrans edge MLP (bf16 MFMA, CK=64) + segmented ALL-ATOMIC scatter ---
// tile 64 dst-sorted edges x 128 out, K=384 in 6 chunks of 64.
// T14 pipeline: chunk c+1's global loads issue right after chunk c's LDS writes, so
// gather latency hides under chunk c's MFMA + barriers (reg-staged: W 4xuint4, z 4xfloat4).
// LDS: W 16KB @0 + z 8KB @16384 (staging) | msg bf16 [64e][128c] swizzled @0 (epilogue).
__global__ __launch_bounds__(256) void k_pretrans(
    const float* __restrict__ nf, const float* __restrict__ ef,
    const unsigned short* __restrict__ wpT, const float* __restrict__ bp,
    const int* __restrict__ src, const int* __restrict__ dst,
    const int* __restrict__ perm,
    float* s1, float* s2, float* mx, float* mn)
{
    __shared__ __align__(16) char smem[24576];
    __shared__ int pidx[64], sidx[64], didx[64];
    __shared__ int seg_start[65], seg_dst[64];
    __shared__ int nseg_s;
    __shared__ float sb[128];

    int t = threadIdx.x;
    int e0 = blockIdx.x * 64;
    if (t < 64) {
        int pe = perm[e0 + t];
        pidx[t] = pe; sidx[t] = src[pe]; didx[t] = dst[pe];
    }
    if (t < 128) sb[t] = bp[t];
    __syncthreads();

    int w  = t >> 6;   // wave 0..3 -> channels w*32..w*32+31
    int l  = t & 63;
    int lr = l & 15;
    int lg = l >> 4;

    f32x4 acc[2][4];
    #pragma unroll
    for (int i = 0; i < 2; ++i)
        #pragma unroll
        for (int j = 0; j < 4; ++j) acc[i][j] = (f32x4){0.f, 0.f, 0.f, 0.f};

    // ---- T14 prologue: issue chunk-0 loads into registers ----
    uint4  wreg[4];
    float4 zreg[4];
    #pragma unroll
    for (int p = 0; p < 4; ++p) {
        int g = t + 256 * p;
        int c = g >> 3, j = g & 7;
        wreg[p] = *(const uint4*)(wpT + (size_t)c * 384 + 0 * 64 + j * 8);
    }
    #pragma unroll
    for (int p = 0; p < 4; ++p) {
        int g = t + 256 * p;
        int e = g >> 4, q = g & 15;
        zreg[p] = *(const float4*)(nf + (size_t)sidx[e] * D + q * 4);  // chunk0: src, colOff 0
    }

    for (int chunk = 0; chunk < 6; ++chunk) {
        // ---- write-late: regs (chunk c) -> LDS ----
        #pragma unroll
        for (int p = 0; p < 4; ++p) {
            int g = t + 256 * p;
            int c = g >> 3, j = g & 7;
            *(uint4*)(smem + c * 128 + ((j * 16) ^ ((c & 7) << 4))) = wreg[p];
        }
        #pragma unroll
        for (int p = 0; p < 4; ++p) {
            int g = t + 256 * p;
            int e = g >> 4, q = g & 15;
            uint2 hv = { pk2bf(zreg[p].x, zreg[p].y), pk2bf(zreg[p].z, zreg[p].w) };
            *(uint2*)(smem + 16384 + e * 128 + ((q * 8) ^ ((e & 7) << 4))) = hv;
        }
        // ---- issue-early: chunk c+1 global loads ----
        if (chunk < 5) {
            int nc = chunk + 1;
            #pragma unroll
            for (int p = 0; p < 4; ++p) {
                int g = t + 256 * p;
                int c = g >> 3, j = g & 7;
                wreg[p] = *(const uint4*)(wpT + (size_t)c * 384 + nc * 64 + j * 8);
            }
            int sel = nc >> 1, colOff = (nc & 1) * 64;
            #pragma unroll
            for (int p = 0; p < 4; ++p) {
                int g = t + 256 * p;
                int e = g >> 4, q = g & 15;
                const float* srcp;
                if (sel == 0)      srcp = nf + (size_t)sidx[e] * D + colOff + q * 4;
                else if (sel == 1) srcp = nf + (size_t)didx[e] * D + colOff + q * 4;
                else               srcp = ef + (size_t)pidx[e] * D + colOff + q * 4;
                zreg[p] = *(const float4*)srcp;
            }
        }
        __syncthreads();
        // ---- MFMA phase on chunk c (unchanged) ----
        #pragma unroll
        for (int ks = 0; ks < 2; ++ks) {
            bf16x8 afr[2], bfr[4];
            int kb = ks * 64 + lg * 16;
            #pragma unroll
            for (int cf = 0; cf < 2; ++cf) {
                int c = w * 32 + cf * 16 + lr;
                afr[cf] = *(const bf16x8*)(smem + c * 128 + (kb ^ ((c & 7) << 4)));
            }
            #pragma unroll
            for (int eb = 0; eb < 4; ++eb) {
                int e = eb * 16 + lr;
                bfr[eb] = *(const bf16x8*)(smem + 16384 + e * 128 + (kb ^ ((e & 7) << 4)));
            }
            #pragma unroll
            for (int cf = 0; cf < 2; ++cf)
                #pragma unroll
                for (int eb = 0; eb < 4; ++eb)
                    acc[cf][eb] = __builtin_amdgcn_mfma_f32_16x16x32_bf16(
                        afr[cf], bfr[eb], acc[cf][eb], 0, 0, 0);
        }
        __syncthreads();   // MFMA done reading LDS; next iter may overwrite
    }

    // ---- epilogue: bias+relu -> msg bf16 [e][c] swizzled: byte = e*256 + ((2c)^((e&7)<<4)) ----
    #pragma unroll
    for (int cf = 0; cf < 2; ++cf)
        #pragma unroll
        for (int eb = 0; eb < 4; ++eb) {
            int e  = eb * 16 + lr;
            int c0 = w * 32 + cf * 16 + lg * 4;   // D row = (lane>>4)*4+reg
            float v0 = fmaxf(acc[cf][eb][0] + sb[c0 + 0], 0.f);
            float v1 = fmaxf(acc[cf][eb][1] + sb[c0 + 1], 0.f);
            float v2 = fmaxf(acc[cf][eb][2] + sb[c0 + 2], 0.f);
            float v3 = fmaxf(acc[cf][eb][3] + sb[c0 + 3], 0.f);
            uint2 mv = { pk2bf(v0, v1), pk2bf(v2, v3) };
            *(uint2*)(smem + e * 256 + ((c0 * 2) ^ ((e & 7) << 4))) = mv;
        }
    if (t == 0) {
        int ns = 0;
        for (int e = 0; e < 64; ++e) {
            if (e == 0 || didx[e] != didx[e - 1]) { seg_dst[ns] = didx[e]; seg_start[ns] = e; ++ns; }
        }
        seg_start[ns] = 64; nseg_s = ns;
    }
    __syncthreads();
    int nseg = nseg_s;
    for (int idx = t; idx < nseg * D; idx += 256) {
        int sg = idx >> 7, c = idx & 127;
        int eb2 = seg_start[sg], ee = seg_start[sg + 1];
        float s = 0.f, q = 0.f, vmax = 0.f, vmin = __int_as_float(0x7f800000);
        for (int e = eb2; e < ee; ++e) {
            float v = bf2f(*(const unsigned short*)(smem + e * 256 + ((c * 2) ^ ((e & 7) << 4))));
            s += v; q += v * v;
            vmax = fmaxf(vmax, v); vmin = fminf(vmin, v);
        }
        size_t base = (size_t)seg_dst[sg] * D + c;
        atomicAdd(&s1[base], s);
        atomicAdd(&s2[base], q);
        atomicMax((int*)&mx[base], __float_as_int(vmax));  // msg >= 0
        atomicMin((int*)&mn[base], __float_as_int(vmin));
    }
}

// ---------------- finalize aggregators in-place + per-node scalers ----------------
__global__ void k_finalize(float* s1, float* s2, float* mx, float* mn,
                           const int* __restrict__ hist, float* scal) {
    size_t idx = (size_t)blockIdx.x * blockDim.x + threadIdx.x;
    if (idx >= (size_t)N_NODES * D) return;
    int n = (int)(idx >> 7);
    int c = (int)(idx & 127);
    float dg = (float)hist[n];
    float ds = fmaxf(dg, 1.f);
    float m  = s1[idx] / ds;
    float var = fmaxf(s2[idx] / ds - m * m, 0.f);
    float sd  = sqrtf(var + EPS);
    bool nb = dg > 0.f;
    s1[idx] = m;
    mx[idx] = nb ? mx[idx] : 0.f;
    mn[idx] = nb ? mn[idx] : 0.f;
    s2[idx] = sd;
    if (c == 0) {
        float logd = logf(dg + 1.f);
        scal[2 * n]     = logd / AVG_D_LOG;
        scal[2 * n + 1] = AVG_D_LOG / fmaxf(logd, EPS);
    }
}

// ---------------- posttrans1 (bf16 MFMA): h1 = relu(h @ w_post1 + b1) -> bf16 ----
__global__ __launch_bounds__(256, 3) void k_post1(
    const float* __restrict__ nf,
    const float* __restrict__ amean, const float* __restrict__ amax,
    const float* __restrict__ amin,  const float* __restrict__ astd,
    const float* __restrict__ scal,
    const unsigned short* __restrict__ w1T, const float* __restrict__ b1,
    unsigned short* __restrict__ h1bf)
{
    __shared__ __align__(16) char smem[49152]; // W 32KB @0, B 16KB @32768
    __shared__ float samp[64], satt[64], sb[128];

    int t = threadIdx.x;
    int n0 = blockIdx.x * 64;
    if (t < 64) {
        int n = n0 + t;
        samp[t] = (n < N_NODES) ? scal[2 * n] : 0.f;
        satt[t] = (n < N_NODES) ? scal[2 * n + 1] : 0.f;
    }
    if (t < 128) sb[t] = b1[t];
    __syncthreads();

    int w  = t >> 6, l = t & 63, lr = l & 15, lg = l >> 4;
    f32x4 acc[2][4];
    #pragma unroll
    for (int i = 0; i < 2; ++i)
        #pragma unroll
        for (int j = 0; j < 4; ++j) acc[i][j] = (f32x4){0.f, 0.f, 0.f, 0.f};

    for (int chunk = 0; chunk < 13; ++chunk) {
        // W chunk [128 c][128 k]
        #pragma unroll
        for (int p = 0; p < 8; ++p) {
            int g = t + 256 * p;
            int c = g >> 4, j = g & 15;
            uint4 wv = *(const uint4*)(w1T + (size_t)c * 1664 + chunk * 128 + j * 8);
            *(uint4*)(smem + c * 256 + ((j * 16) ^ ((c & 7) << 4))) = wv;
        }
        // B chunk [64 n][128 k] with fused scaling
        const float* base;
        int r;
        if (chunk == 0) { base = nf; r = 0; }
        else {
            int b = (chunk - 1) & 3;
            r = (chunk - 1) >> 2;   // 0:identity, 1:amp, 2:att
            base = (b == 0) ? amean : (b == 1) ? amax : (b == 2) ? amin : astd;
        }
        #pragma unroll
        for (int p = 0; p < 8; ++p) {
            int g = t + 256 * p;
            int e = g >> 5, q = g & 31;
            int n = n0 + e;
            float4 fv = {0.f, 0.f, 0.f, 0.f};
            if (n < N_NODES) {
                fv = *(const float4*)(base + (size_t)n * D + q * 4);
                if (r == 1) { float sc = samp[e]; fv.x *= sc; fv.y *= sc; fv.z *= sc; fv.w *= sc; }
                else if (r == 2) { float sc = satt[e]; fv.x *= sc; fv.y *= sc; fv.z *= sc; fv.w *= sc; }
            }
            uint2 hv = { pk2bf(fv.x, fv.y), pk2bf(fv.z, fv.w) };
            *(uint2*)(smem + 32768 + e * 256 + ((q * 8) ^ ((e & 7) << 4))) = hv;
        }
        __syncthreads();
        #pragma unroll
        for (int ks = 0; ks < 4; ++ks) {
            bf16x8 afr[2], bfr[4];
            int kb = ks * 64 + lg * 16;
            #pragma unroll
            for (int cf = 0; cf < 2; ++cf) {
                int c = w * 32 + cf * 16 + lr;
                afr[cf] = *(const bf16x8*)(smem + c * 256 + (kb ^ ((c & 7) << 4)));
            }
            #pragma unroll
            for (int eb = 0; eb < 4; ++eb) {
                int e = eb * 16 + lr;
                bfr[eb] = *(const bf16x8*)(smem + 32768 + e * 256 + (kb ^ ((e & 7) << 4)));
            }
            #pragma unroll
            for (int cf = 0; cf < 2; ++cf)
                #pragma unroll
                for (int eb = 0; eb < 4; ++eb)
                    acc[cf][eb] = __builtin_amdgcn_mfma_f32_16x16x32_bf16(
                        afr[cf], bfr[eb], acc[cf][eb], 0, 0, 0);
        }
        __syncthreads();
    }

    // epilogue: relu(acc + b1) -> h1 bf16
    #pragma unroll
    for (int cf = 0; cf < 2; ++cf)
        #pragma unroll
        for (int eb = 0; eb < 4; ++eb) {
            int n = n0 + eb * 16 + lr;
            if (n < N_NODES) {
                int c0 = w * 32 + cf * 16 + lg * 4;
                float v0 = fmaxf(acc[cf][eb][0] + sb[c0 + 0], 0.f);
                float v1 = fmaxf(acc[cf][eb][1] + sb[c0 + 1], 0.f);
                float v2 = fmaxf(acc[cf][eb][2] + sb[c0 + 2], 0.f);
                float v3 = fmaxf(acc[cf][eb][3] + sb[c0 + 3], 0.f);
                uint2 hv = { pk2bf(v0, v1), pk2bf(v2, v3) };
                *(uint2*)(h1bf + (size_t)n * D + c0) = hv;
            }
        }
}

// ---------------- posttrans2 (bf16 MFMA): out = h1 @ w_post2 + b2 + nf ----------------
__global__ __launch_bounds__(256, 3) void k_post2(
    const unsigned short* __restrict__ h1bf, const unsigned short* __restrict__ w2T,
    const float* __restrict__ b2, const float* __restrict__ nf,
    float* __restrict__ out)
{
    __shared__ __align__(16) char smem[49152]; // W 32KB @0, B 16KB @32768
    __shared__ float sb[128];

    int t = threadIdx.x;
    int n0 = blockIdx.x * 64;
    if (t < 128) sb[t] = b2[t];

    int w  = t >> 6, l = t & 63, lr = l & 15, lg = l >> 4;
    f32x4 acc[2][4];
    #pragma unroll
    for (int i = 0; i < 2; ++i)
        #pragma unroll
        for (int j = 0; j < 4; ++j) acc[i][j] = (f32x4){0.f, 0.f, 0.f, 0.f};

    // stage W2 [128][128]
    #pragma unroll
    for (int p = 0; p < 8; ++p) {
        int g = t + 256 * p;
        int c = g >> 4, j = g & 15;
        uint4 wv = *(const uint4*)(w2T + (size_t)c * 128 + j * 8);
        *(uint4*)(smem + c * 256 + ((j * 16) ^ ((c & 7) << 4))) = wv;
    }
    // stage B = h1 [64 n][128 k] bf16
    #pragma unroll
    for (int p = 0; p < 4; ++p) {
        int g = t + 256 * p;
        int e = g >> 4, j = g & 15;
        int n = n0 + e;
        uint4 hv = {0u, 0u, 0u, 0u};
        if (n < N_NODES) hv = *(const uint4*)(h1bf + (size_t)n * D + j * 8);
        *(uint4*)(smem + 32768 + e * 256 + ((j * 16) ^ ((e & 7) << 4))) = hv;
    }
    __syncthreads();
    #pragma unroll
    for (int ks = 0; ks < 4; ++ks) {
        bf16x8 afr[2], bfr[4];
        int kb = ks * 64 + lg * 16;
        #pragma unroll
        for (int cf = 0; cf < 2; ++cf) {
            int c = w * 32 + cf * 16 + lr;
            afr[cf] = *(const bf16x8*)(smem + c * 256 + (kb ^ ((c & 7) << 4)));
        }
        #pragma unroll
        for (int eb = 0; eb < 4; ++eb) {
            int e = eb * 16 + lr;
            bfr[eb] = *(const bf16x8*)(smem + 32768 + e * 256 + (kb ^ ((e & 7) << 4)));
        }
        #pragma unroll
        for (int cf = 0; cf < 2; ++cf)
            #pragma unroll
            for (int eb = 0; eb < 4; ++eb)
                acc[cf][eb] = __builtin_amdgcn_mfma_f32_16x16x32_bf16(
                    afr[cf], bfr[eb], acc[cf][eb], 0, 0, 0);
    }

    // epilogue: + b2 + nf residual (fp32), direct store
    #pragma unroll
    for (int cf = 0; cf < 2; ++cf)
        #pragma unroll
        for (int eb = 0; eb < 4; ++eb) {
            int n = n0 + eb * 16 + lr;
            if (n < N_NODES) {
                int c0 = w * 32 + cf * 16 + lg * 4;
                float4 rv = *(const float4*)(nf + (size_t)n * D + c0);
                float4 ov = { acc[cf][eb][0] + sb[c0 + 0] + rv.x,
                              acc[cf][eb][1] + sb[c0 + 1] + rv.y,
                              acc[cf][eb][2] + sb[c0 + 2] + rv.z,
                              acc[cf][eb][3] + sb[c0 + 3] + rv.w };
                *(float4*)(out + (size_t)n * D + c0) = ov;
            }
        }
}

extern "C" void kernel_launch(void* const* d_in, const int* in_sizes, int n_in,
                              void* d_out, int out_size, void* d_ws, size_t ws_size,
                              hipStream_t stream) {
    const float* nf = (const float*)d_in[0];
    const float* ef = (const float*)d_in[1];
    const float* wp = (const float*)d_in[2];
    const float* bp = (const float*)d_in[3];
    const float* w1 = (const float*)d_in[4];
    const float* b1 = (const float*)d_in[5];
    const float* w2 = (const float*)d_in[6];
    const float* b2 = (const float*)d_in[7];
    const int* src  = (const int*)d_in[8];
    const int* dst  = (const int*)d_in[9];
    float* out = (float*)d_out;

    const size_t ND = (size_t)N_NODES * D;  // 6.4M
    float* ws     = (float*)d_ws;
    int*   hist   = (int*)ws;                         // 50048
    int*   cursor = hist + 50048;                     // 50048
    int*   perm   = cursor + 50048;                   // 800000
    unsigned short* wpT = (unsigned short*)(perm + N_EDGES);  // 128*384
    unsigned short* w1T = wpT + 49152;                // 128*1664
    unsigned short* w2T = w1T + 212992;               // 128*128
    float* s1     = (float*)(w2T + 16384);            // ND -> mean
    float* s2     = s1 + ND;                          // ND -> std
    float* mx     = s2 + ND;                          // ND -> max
    float* mn     = mx + ND;                          // ND -> min
    float* scal   = mn + ND;                          // 2N (padded 100096)
    unsigned short* h1bf = (unsigned short*)(scal + 100096);  // ND bf16

    hipLaunchKernelGGL(k_init, dim3(2048), dim3(256), 0, stream, hist, s1, s2, mx, mn);
    hipLaunchKernelGGL(k_hist, dim3((N_EDGES + 255) / 256), dim3(256), 0, stream, dst, hist);
    hipLaunchKernelGGL(k_scan, dim3(1), dim3(256), 0, stream, hist, cursor);
    hipLaunchKernelGGL(k_scatter, dim3((N_EDGES + 255) / 256), dim3(256), 0, stream, dst, cursor, perm);
    hipLaunchKernelGGL(k_prepT, dim3(192), dim3(256), 0, stream, wp, wpT, 384);
    hipLaunchKernelGGL(k_prepT, dim3(832), dim3(256), 0, stream, w1, w1T, 1664);
    hipLaunchKernelGGL(k_prepT, dim3(64),  dim3(256), 0, stream, w2, w2T, 128);
    hipLaunchKernelGGL(k_pretrans, dim3(N_EDGES / 64), dim3(256), 0, stream,
                       nf, ef, wpT, bp, src, dst, perm, s1, s2, mx, mn);
    hipLaunchKernelGGL(k_finalize, dim3((unsigned)((ND + 255) / 256)), dim3(256), 0, stream,
                       s1, s2, mx, mn, hist, scal);
    hipLaunchKernelGGL(k_post1, dim3((N_NODES + 63) / 64), dim3(256), 0, stream,
                       nf, s1, mx, mn, s2, scal, w1T, b1, h1bf);
    hipLaunchKernelGGL(k_post2, dim3((N_NODES + 63) / 64), dim3(256), 0, stream,
                       h1bf, w2T, b2, nf, out);
}

// Round 8
// 608.774 us; speedup vs baseline: 1.2742x; 1.2742x over previous
//
#include <hip/hip_runtime.h>
#include <math.h>

#define N_NODES 50000
#define N_EDGES 800000
#define D 128
#define AVG_D_LOG 2.833213344056216f  /* log(17.0) */
#define EPS 1e-5f

typedef __attribute__((ext_vector_type(8))) short bf16x8;
typedef __attribute__((ext_vector_type(4))) float f32x4;

__device__ __forceinline__ unsigned short f2bf(float x) {
    unsigned u = __float_as_uint(x);
    u += 0x7fffu + ((u >> 16) & 1u);
    return (unsigned short)(u >> 16);
}
__device__ __forceinline__ unsigned pk2bf(float a, float b) {
    return (unsigned)f2bf(a) | ((unsigned)f2bf(b) << 16);
}
__device__ __forceinline__ float bf2f(unsigned short u) {
    return __uint_as_float(((unsigned)u) << 16);
}

// ---------------- init: zero accumulators, +inf for min, zero hist ----------------
__global__ void k_init(int* hist, float* s1, float* s2, float* mx, float* mn) {
    size_t stride = (size_t)gridDim.x * blockDim.x;
    size_t i0 = (size_t)blockIdx.x * blockDim.x + threadIdx.x;
    const size_t ND4 = (size_t)N_NODES * D / 4;
    float4 z4 = {0.f, 0.f, 0.f, 0.f};
    int4 inf4 = {0x7f800000, 0x7f800000, 0x7f800000, 0x7f800000};
    for (size_t t = i0; t < ND4; t += stride) {
        ((float4*)s1)[t] = z4; ((float4*)s2)[t] = z4; ((float4*)mx)[t] = z4;
        ((int4*)mn)[t] = inf4;
    }
    for (size_t t = i0; t < N_NODES; t += stride) hist[t] = 0;
}

// ---------------- CSR build ----------------
__global__ void k_hist(const int* __restrict__ dst, int* hist) {
    int e = blockIdx.x * blockDim.x + threadIdx.x;
    if (e < N_EDGES) atomicAdd(&hist[dst[e]], 1);
}

__global__ void k_scan(const int* __restrict__ hist, int* cursor) {
    __shared__ int part[256];
    __shared__ int base_s[256];
    int t = threadIdx.x;
    const int chunk = (N_NODES + 255) / 256;
    int lo = t * chunk;
    int hi = lo + chunk; if (hi > N_NODES) hi = N_NODES;
    int s = 0;
    for (int i = lo; i < hi; ++i) s += hist[i];
    part[t] = s;
    __syncthreads();
    if (t == 0) {
        int run = 0;
        for (int i = 0; i < 256; ++i) { base_s[i] = run; run += part[i]; }
    }
    __syncthreads();
    int run = base_s[t];
    for (int i = lo; i < hi; ++i) { cursor[i] = run; run += hist[i]; }
}

__global__ void k_scatter(const int* __restrict__ dst, int* cursor, int* perm) {
    int e = blockIdx.x * blockDim.x + threadIdx.x;
    if (e < N_EDGES) {
        int pos = atomicAdd(&cursor[dst[e]], 1);
        perm[pos] = e;
    }
}

// ---------------- one-time: W [K][128] fp32 -> WT [128][K] bf16 ----------------
__global__ void k_prepT(const float* __restrict__ w, unsigned short* __restrict__ wT, int K) {
    int idx = blockIdx.x * blockDim.x + threadIdx.x;
    if (idx >= K * D) return;
    int k = idx >> 7, c = idx & 127;
    wT[(size_t)c * K + k] = f2bf(w[idx]);
}

// ---------------- pretrans edge MLP (bf16 MFMA, CK=64) + segmented ALL-ATOMIC scatter ---
// tile 64 dst-sorted edges x 128 out, K=384 in 6 chunks of 64 (fully unrolled).
// T14 spill-proof: prefetch for chunk c+1 held in 8 NAMED uint4/float4 SSA values
// (no arrays -> no scratch demotion; round-7's WRITE_SIZE 5x was exactly that spill).
// LDS: W 16KB @0 + z 8KB @16384 (staging) | msg bf16 [64e][128c] swizzled @0 (epilogue).
__global__ __launch_bounds__(256) void k_pretrans(
    const float* __restrict__ nf, const float* __restrict__ ef,
    const unsigned short* __restrict__ wpT, const float* __restrict__ bp,
    const int* __restrict__ src, const int* __restrict__ dst,
    const int* __restrict__ perm,
    float* s1, float* s2, float* mx, float* mn)
{
    __shared__ __align__(16) char smem[24576];
    __shared__ int pidx[64], sidx[64], didx[64];
    __shared__ int seg_start[65], seg_dst[64];
    __shared__ int nseg_s;
    __shared__ float sb[128];

    int t = threadIdx.x;
    int e0 = blockIdx.x * 64;
    if (t < 64) {
        int pe = perm[e0 + t];
        pidx[t] = pe; sidx[t] = src[pe]; didx[t] = dst[pe];
    }
    if (t < 128) sb[t] = bp[t];
    __syncthreads();

    int w  = t >> 6;   // wave 0..3 -> channels w*32..w*32+31
    int l  = t & 63;
    int lr = l & 15;
    int lg = l >> 4;

    f32x4 acc[2][4];
    #pragma unroll
    for (int i = 0; i < 2; ++i)
        #pragma unroll
        for (int j = 0; j < 4; ++j) acc[i][j] = (f32x4){0.f, 0.f, 0.f, 0.f};

    uint4  pw0, pw1, pw2, pw3;
    float4 pz0, pz1, pz2, pz3;

#define ZROW(NC, e) ((NC) < 2 ? nf + (size_t)sidx[e] * D : \
                     (NC) < 4 ? nf + (size_t)didx[e] * D : \
                                ef + (size_t)pidx[e] * D)

#define PF(NC) do { \
    { int g = t;       int c = g >> 3, j = g & 7;  pw0 = *(const uint4*)(wpT + (size_t)c * 384 + (NC) * 64 + j * 8); } \
    { int g = t + 256; int c = g >> 3, j = g & 7;  pw1 = *(const uint4*)(wpT + (size_t)c * 384 + (NC) * 64 + j * 8); } \
    { int g = t + 512; int c = g >> 3, j = g & 7;  pw2 = *(const uint4*)(wpT + (size_t)c * 384 + (NC) * 64 + j * 8); } \
    { int g = t + 768; int c = g >> 3, j = g & 7;  pw3 = *(const uint4*)(wpT + (size_t)c * 384 + (NC) * 64 + j * 8); } \
    { int g = t;       int e = g >> 4, q = g & 15; pz0 = *(const float4*)(ZROW(NC, e) + (((NC) & 1) * 64) + q * 4); } \
    { int g = t + 256; int e = g >> 4, q = g & 15; pz1 = *(const float4*)(ZROW(NC, e) + (((NC) & 1) * 64) + q * 4); } \
    { int g = t + 512; int e = g >> 4, q = g & 15; pz2 = *(const float4*)(ZROW(NC, e) + (((NC) & 1) * 64) + q * 4); } \
    { int g = t + 768; int e = g >> 4, q = g & 15; pz3 = *(const float4*)(ZROW(NC, e) + (((NC) & 1) * 64) + q * 4); } \
} while (0)

#define WR() do { \
    { int g = t;       int c = g >> 3, j = g & 7;  *(uint4*)(smem + c * 128 + ((j * 16) ^ ((c & 7) << 4))) = pw0; } \
    { int g = t + 256; int c = g >> 3, j = g & 7;  *(uint4*)(smem + c * 128 + ((j * 16) ^ ((c & 7) << 4))) = pw1; } \
    { int g = t + 512; int c = g >> 3, j = g & 7;  *(uint4*)(smem + c * 128 + ((j * 16) ^ ((c & 7) << 4))) = pw2; } \
    { int g = t + 768; int c = g >> 3, j = g & 7;  *(uint4*)(smem + c * 128 + ((j * 16) ^ ((c & 7) << 4))) = pw3; } \
    { int g = t;       int e = g >> 4, q = g & 15; uint2 hv = { pk2bf(pz0.x, pz0.y), pk2bf(pz0.z, pz0.w) }; \
      *(uint2*)(smem + 16384 + e * 128 + ((q * 8) ^ ((e & 7) << 4))) = hv; } \
    { int g = t + 256; int e = g >> 4, q = g & 15; uint2 hv = { pk2bf(pz1.x, pz1.y), pk2bf(pz1.z, pz1.w) }; \
      *(uint2*)(smem + 16384 + e * 128 + ((q * 8) ^ ((e & 7) << 4))) = hv; } \
    { int g = t + 512; int e = g >> 4, q = g & 15; uint2 hv = { pk2bf(pz2.x, pz2.y), pk2bf(pz2.z, pz2.w) }; \
      *(uint2*)(smem + 16384 + e * 128 + ((q * 8) ^ ((e & 7) << 4))) = hv; } \
    { int g = t + 768; int e = g >> 4, q = g & 15; uint2 hv = { pk2bf(pz3.x, pz3.y), pk2bf(pz3.z, pz3.w) }; \
      *(uint2*)(smem + 16384 + e * 128 + ((q * 8) ^ ((e & 7) << 4))) = hv; } \
} while (0)

#define MM() do { \
    _Pragma("unroll") \
    for (int ks = 0; ks < 2; ++ks) { \
        bf16x8 afr[2], bfr[4]; \
        int kb = ks * 64 + lg * 16; \
        _Pragma("unroll") \
        for (int cf = 0; cf < 2; ++cf) { \
            int c = w * 32 + cf * 16 + lr; \
            afr[cf] = *(const bf16x8*)(smem + c * 128 + (kb ^ ((c & 7) << 4))); \
        } \
        _Pragma("unroll") \
        for (int eb = 0; eb < 4; ++eb) { \
            int e = eb * 16 + lr; \
            bfr[eb] = *(const bf16x8*)(smem + 16384 + e * 128 + (kb ^ ((e & 7) << 4))); \
        } \
        _Pragma("unroll") \
        for (int cf = 0; cf < 2; ++cf) \
            _Pragma("unroll") \
            for (int eb = 0; eb < 4; ++eb) \
                acc[cf][eb] = __builtin_amdgcn_mfma_f32_16x16x32_bf16( \
                    afr[cf], bfr[eb], acc[cf][eb], 0, 0, 0); \
    } \
} while (0)

    PF(0);
    WR(); PF(1); __syncthreads(); MM(); __syncthreads();
    WR(); PF(2); __syncthreads(); MM(); __syncthreads();
    WR(); PF(3); __syncthreads(); MM(); __syncthreads();
    WR(); PF(4); __syncthreads(); MM(); __syncthreads();
    WR(); PF(5); __syncthreads(); MM(); __syncthreads();
    WR();        __syncthreads(); MM(); __syncthreads();

#undef ZROW
#undef PF
#undef WR
#undef MM

    // ---- epilogue: bias+relu -> msg bf16 [e][c] swizzled: byte = e*256 + ((2c)^((e&7)<<4)) ----
    #pragma unroll
    for (int cf = 0; cf < 2; ++cf)
        #pragma unroll
        for (int eb = 0; eb < 4; ++eb) {
            int e  = eb * 16 + lr;
            int c0 = w * 32 + cf * 16 + lg * 4;   // D row = (lane>>4)*4+reg
            float v0 = fmaxf(acc[cf][eb][0] + sb[c0 + 0], 0.f);
            float v1 = fmaxf(acc[cf][eb][1] + sb[c0 + 1], 0.f);
            float v2 = fmaxf(acc[cf][eb][2] + sb[c0 + 2], 0.f);
            float v3 = fmaxf(acc[cf][eb][3] + sb[c0 + 3], 0.f);
            uint2 mv = { pk2bf(v0, v1), pk2bf(v2, v3) };
            *(uint2*)(smem + e * 256 + ((c0 * 2) ^ ((e & 7) << 4))) = mv;
        }
    if (t == 0) {
        int ns = 0;
        for (int e = 0; e < 64; ++e) {
            if (e == 0 || didx[e] != didx[e - 1]) { seg_dst[ns] = didx[e]; seg_start[ns] = e; ++ns; }
        }
        seg_start[ns] = 64; nseg_s = ns;
    }
    __syncthreads();
    int nseg = nseg_s;
    for (int idx = t; idx < nseg * D; idx += 256) {
        int sg = idx >> 7, c = idx & 127;
        int eb2 = seg_start[sg], ee = seg_start[sg + 1];
        float s = 0.f, q = 0.f, vmax = 0.f, vmin = __int_as_float(0x7f800000);
        for (int e = eb2; e < ee; ++e) {
            float v = bf2f(*(const unsigned short*)(smem + e * 256 + ((c * 2) ^ ((e & 7) << 4))));
            s += v; q += v * v;
            vmax = fmaxf(vmax, v); vmin = fminf(vmin, v);
        }
        size_t base = (size_t)seg_dst[sg] * D + c;
        atomicAdd(&s1[base], s);
        atomicAdd(&s2[base], q);
        atomicMax((int*)&mx[base], __float_as_int(vmax));  // msg >= 0
        atomicMin((int*)&mn[base], __float_as_int(vmin));
    }
}

// ---------------- finalize aggregators in-place + per-node scalers ----------------
__global__ void k_finalize(float* s1, float* s2, float* mx, float* mn,
                           const int* __restrict__ hist, float* scal) {
    size_t idx = (size_t)blockIdx.x * blockDim.x + threadIdx.x;
    if (idx >= (size_t)N_NODES * D) return;
    int n = (int)(idx >> 7);
    int c = (int)(idx & 127);
    float dg = (float)hist[n];
    float ds = fmaxf(dg, 1.f);
    float m  = s1[idx] / ds;
    float var = fmaxf(s2[idx] / ds - m * m, 0.f);
    float sd  = sqrtf(var + EPS);
    bool nb = dg > 0.f;
    s1[idx] = m;
    mx[idx] = nb ? mx[idx] : 0.f;
    mn[idx] = nb ? mn[idx] : 0.f;
    s2[idx] = sd;
    if (c == 0) {
        float logd = logf(dg + 1.f);
        scal[2 * n]     = logd / AVG_D_LOG;
        scal[2 * n + 1] = AVG_D_LOG / fmaxf(logd, EPS);
    }
}

// ---------------- posttrans1 (bf16 MFMA): h1 = relu(h @ w_post1 + b1) -> bf16 ----
__global__ __launch_bounds__(256, 3) void k_post1(
    const float* __restrict__ nf,
    const float* __restrict__ amean, const float* __restrict__ amax,
    const float* __restrict__ amin,  const float* __restrict__ astd,
    const float* __restrict__ scal,
    const unsigned short* __restrict__ w1T, const float* __restrict__ b1,
    unsigned short* __restrict__ h1bf)
{
    __shared__ __align__(16) char smem[49152]; // W 32KB @0, B 16KB @32768
    __shared__ float samp[64], satt[64], sb[128];

    int t = threadIdx.x;
    int n0 = blockIdx.x * 64;
    if (t < 64) {
        int n = n0 + t;
        samp[t] = (n < N_NODES) ? scal[2 * n] : 0.f;
        satt[t] = (n < N_NODES) ? scal[2 * n + 1] : 0.f;
    }
    if (t < 128) sb[t] = b1[t];
    __syncthreads();

    int w  = t >> 6, l = t & 63, lr = l & 15, lg = l >> 4;
    f32x4 acc[2][4];
    #pragma unroll
    for (int i = 0; i < 2; ++i)
        #pragma unroll
        for (int j = 0; j < 4; ++j) acc[i][j] = (f32x4){0.f, 0.f, 0.f, 0.f};

    for (int chunk = 0; chunk < 13; ++chunk) {
        // W chunk [128 c][128 k]
        #pragma unroll
        for (int p = 0; p < 8; ++p) {
            int g = t + 256 * p;
            int c = g >> 4, j = g & 15;
            uint4 wv = *(const uint4*)(w1T + (size_t)c * 1664 + chunk * 128 + j * 8);
            *(uint4*)(smem + c * 256 + ((j * 16) ^ ((c & 7) << 4))) = wv;
        }
        // B chunk [64 n][128 k] with fused scaling
        const float* base;
        int r;
        if (chunk == 0) { base = nf; r = 0; }
        else {
            int b = (chunk - 1) & 3;
            r = (chunk - 1) >> 2;   // 0:identity, 1:amp, 2:att
            base = (b == 0) ? amean : (b == 1) ? amax : (b == 2) ? amin : astd;
        }
        #pragma unroll
        for (int p = 0; p < 8; ++p) {
            int g = t + 256 * p;
            int e = g >> 5, q = g & 31;
            int n = n0 + e;
            float4 fv = {0.f, 0.f, 0.f, 0.f};
            if (n < N_NODES) {
                fv = *(const float4*)(base + (size_t)n * D + q * 4);
                if (r == 1) { float sc = samp[e]; fv.x *= sc; fv.y *= sc; fv.z *= sc; fv.w *= sc; }
                else if (r == 2) { float sc = satt[e]; fv.x *= sc; fv.y *= sc; fv.z *= sc; fv.w *= sc; }
            }
            uint2 hv = { pk2bf(fv.x, fv.y), pk2bf(fv.z, fv.w) };
            *(uint2*)(smem + 32768 + e * 256 + ((q * 8) ^ ((e & 7) << 4))) = hv;
        }
        __syncthreads();
        #pragma unroll
        for (int ks = 0; ks < 4; ++ks) {
            bf16x8 afr[2], bfr[4];
            int kb = ks * 64 + lg * 16;
            #pragma unroll
            for (int cf = 0; cf < 2; ++cf) {
                int c = w * 32 + cf * 16 + lr;
                afr[cf] = *(const bf16x8*)(smem + c * 256 + (kb ^ ((c & 7) << 4)));
            }
            #pragma unroll
            for (int eb = 0; eb < 4; ++eb) {
                int e = eb * 16 + lr;
                bfr[eb] = *(const bf16x8*)(smem + 32768 + e * 256 + (kb ^ ((e & 7) << 4)));
            }
            #pragma unroll
            for (int cf = 0; cf < 2; ++cf)
                #pragma unroll
                for (int eb = 0; eb < 4; ++eb)
                    acc[cf][eb] = __builtin_amdgcn_mfma_f32_16x16x32_bf16(
                        afr[cf], bfr[eb], acc[cf][eb], 0, 0, 0);
        }
        __syncthreads();
    }

    // epilogue: relu(acc + b1) -> h1 bf16
    #pragma unroll
    for (int cf = 0; cf < 2; ++cf)
        #pragma unroll
        for (int eb = 0; eb < 4; ++eb) {
            int n = n0 + eb * 16 + lr;
            if (n < N_NODES) {
                int c0 = w * 32 + cf * 16 + lg * 4;
                float v0 = fmaxf(acc[cf][eb][0] + sb[c0 + 0], 0.f);
                float v1 = fmaxf(acc[cf][eb][1] + sb[c0 + 1], 0.f);
                float v2 = fmaxf(acc[cf][eb][2] + sb[c0 + 2], 0.f);
                float v3 = fmaxf(acc[cf][eb][3] + sb[c0 + 3], 0.f);
                uint2 hv = { pk2bf(v0, v1), pk2bf(v2, v3) };
                *(uint2*)(h1bf + (size_t)n * D + c0) = hv;
            }
        }
}

// ---------------- posttrans2 (bf16 MFMA): out = h1 @ w_post2 + b2 + nf ----------------
__global__ __launch_bounds__(256, 3) void k_post2(
    const unsigned short* __restrict__ h1bf, const unsigned short* __restrict__ w2T,
    const float* __restrict__ b2, const float* __restrict__ nf,
    float* __restrict__ out)
{
    __shared__ __align__(16) char smem[49152]; // W 32KB @0, B 16KB @32768
    __shared__ float sb[128];

    int t = threadIdx.x;
    int n0 = blockIdx.x * 64;
    if (t < 128) sb[t] = b2[t];

    int w  = t >> 6, l = t & 63, lr = l & 15, lg = l >> 4;
    f32x4 acc[2][4];
    #pragma unroll
    for (int i = 0; i < 2; ++i)
        #pragma unroll
        for (int j = 0; j < 4; ++j) acc[i][j] = (f32x4){0.f, 0.f, 0.f, 0.f};

    // stage W2 [128][128]
    #pragma unroll
    for (int p = 0; p < 8; ++p) {
        int g = t + 256 * p;
        int c = g >> 4, j = g & 15;
        uint4 wv = *(const uint4*)(w2T + (size_t)c * 128 + j * 8);
        *(uint4*)(smem + c * 256 + ((j * 16) ^ ((c & 7) << 4))) = wv;
    }
    // stage B = h1 [64 n][128 k] bf16
    #pragma unroll
    for (int p = 0; p < 4; ++p) {
        int g = t + 256 * p;
        int e = g >> 4, j = g & 15;
        int n = n0 + e;
        uint4 hv = {0u, 0u, 0u, 0u};
        if (n < N_NODES) hv = *(const uint4*)(h1bf + (size_t)n * D + j * 8);
        *(uint4*)(smem + 32768 + e * 256 + ((j * 16) ^ ((e & 7) << 4))) = hv;
    }
    __syncthreads();
    #pragma unroll
    for (int ks = 0; ks < 4; ++ks) {
        bf16x8 afr[2], bfr[4];
        int kb = ks * 64 + lg * 16;
        #pragma unroll
        for (int cf = 0; cf < 2; ++cf) {
            int c = w * 32 + cf * 16 + lr;
            afr[cf] = *(const bf16x8*)(smem + c * 256 + (kb ^ ((c & 7) << 4)));
        }
        #pragma unroll
        for (int eb = 0; eb < 4; ++eb) {
            int e = eb * 16 + lr;
            bfr[eb] = *(const bf16x8*)(smem + 32768 + e * 256 + (kb ^ ((e & 7) << 4)));
        }
        #pragma unroll
        for (int cf = 0; cf < 2; ++cf)
            #pragma unroll
            for (int eb = 0; eb < 4; ++eb)
                acc[cf][eb] = __builtin_amdgcn_mfma_f32_16x16x32_bf16(
                    afr[cf], bfr[eb], acc[cf][eb], 0, 0, 0);
    }

    // epilogue: + b2 + nf residual (fp32), direct store
    #pragma unroll
    for (int cf = 0; cf < 2; ++cf)
        #pragma unroll
        for (int eb = 0; eb < 4; ++eb) {
            int n = n0 + eb * 16 + lr;
            if (n < N_NODES) {
                int c0 = w * 32 + cf * 16 + lg * 4;
                float4 rv = *(const float4*)(nf + (size_t)n * D + c0);
                float4 ov = { acc[cf][eb][0] + sb[c0 + 0] + rv.x,
                              acc[cf][eb][1] + sb[c0 + 1] + rv.y,
                              acc[cf][eb][2] + sb[c0 + 2] + rv.z,
                              acc[cf][eb][3] + sb[c0 + 3] + rv.w };
                *(float4*)(out + (size_t)n * D + c0) = ov;
            }
        }
}

extern "C" void kernel_launch(void* const* d_in, const int* in_sizes, int n_in,
                              void* d_out, int out_size, void* d_ws, size_t ws_size,
                              hipStream_t stream) {
    const float* nf = (const float*)d_in[0];
    const float* ef = (const float*)d_in[1];
    const float* wp = (const float*)d_in[2];
    const float* bp = (const float*)d_in[3];
    const float* w1 = (const float*)d_in[4];
    const float* b1 = (const float*)d_in[5];
    const float* w2 = (const float*)d_in[6];
    const float* b2 = (const float*)d_in[7];
    const int* src  = (const int*)d_in[8];
    const int* dst  = (const int*)d_in[9];
    float* out = (float*)d_out;

    const size_t ND = (size_t)N_NODES * D;  // 6.4M
    float* ws     = (float*)d_ws;
    int*   hist   = (int*)ws;                         // 50048
    int*   cursor = hist + 50048;                     // 50048
    int*   perm   = cursor + 50048;                   // 800000
    unsigned short* wpT = (unsigned short*)(perm + N_EDGES);  // 128*384
    unsigned short* w1T = wpT + 49152;                // 128*1664
    unsigned short* w2T = w1T + 212992;               // 128*128
    float* s1     = (float*)(w2T + 16384);            // ND -> mean
    float* s2     = s1 + ND;                          // ND -> std
    float* mx     = s2 + ND;                          // ND -> max
    float* mn     = mx + ND;                          // ND -> min
    float* scal   = mn + ND;                          // 2N (padded 100096)
    unsigned short* h1bf = (unsigned short*)(scal + 100096);  // ND bf16

    hipLaunchKernelGGL(k_init, dim3(2048), dim3(256), 0, stream, hist, s1, s2, mx, mn);
    hipLaunchKernelGGL(k_hist, dim3((N_EDGES + 255) / 256), dim3(256), 0, stream, dst, hist);
    hipLaunchKernelGGL(k_scan, dim3(1), dim3(256), 0, stream, hist, cursor);
    hipLaunchKernelGGL(k_scatter, dim3((N_EDGES + 255) / 256), dim3(256), 0, stream, dst, cursor, perm);
    hipLaunchKernelGGL(k_prepT, dim3(192), dim3(256), 0, stream, wp, wpT, 384);
    hipLaunchKernelGGL(k_prepT, dim3(832), dim3(256), 0, stream, w1, w1T, 1664);
    hipLaunchKernelGGL(k_prepT, dim3(64),  dim3(256), 0, stream, w2, w2T, 128);
    hipLaunchKernelGGL(k_pretrans, dim3(N_EDGES / 64), dim3(256), 0, stream,
                       nf, ef, wpT, bp, src, dst, perm, s1, s2, mx, mn);
    hipLaunchKernelGGL(k_finalize, dim3((unsigned)((ND + 255) / 256)), dim3(256), 0, stream,
                       s1, s2, mx, mn, hist, scal);
    hipLaunchKernelGGL(k_post1, dim3((N_NODES + 63) / 64), dim3(256), 0, stream,
                       nf, s1, mx, mn, s2, scal, w1T, b1, h1bf);
    hipLaunchKernelGGL(k_post2, dim3((N_NODES + 63) / 64), dim3(256), 0, stream,
                       h1bf, w2T, b2, nf, out);
}